// Round 20
// baseline (17.202 us; speedup 1.0000x reference)
//
#include <hip/hip_runtime.h>

#define NN 512
#define DD 9
#define LL 32
#define NT 32   // 16x16 tiles per dimension
#define PG 17   // part row stride (u32): odd -> conflict-free epilogue reads

typedef _Float16 f16x8 __attribute__((ext_vector_type(8)));
typedef float    f32x4 __attribute__((ext_vector_type(4)));

// Scan (R13-proven form: unconditional loads, dp/dn rotate pipeline, 60 VGPR,
// no spill — FROZEN). Wave wp owns 4 row-tiles {4wp..4wp+3} of the "a side",
// scans all 32 "b side" tiles. MFMA emits the complete distance (cross hi/lo
// split k0..15, norms k16..19). Tracking: pk = (dbits & ~31)|jj, fminf =
// 2 VALU/cell; per-lane (d_trunc, jj) min == first-index argmin over its col
// set col = (lane&15) + 16*jj (proven exact: R11/R13/R18 absmax 0.0).
__device__ __forceinline__ void min_scan4(const f16x8* __restrict__ sAs,
                                          const f16x8* __restrict__ sBs,
                                          unsigned (* __restrict__ part)[PG],
                                          int wp, int lane)
{
    const int ti0 = wp * 4;
    f16x8 afr[4];
    #pragma unroll
    for (int q = 0; q < 4; ++q) afr[q] = sAs[(ti0 + q) * 64 + lane];

    float bm[16];
    #pragma unroll
    for (int i = 0; i < 16; ++i) bm[i] = 1e30f;

    const f32x4 zero = {0.f, 0.f, 0.f, 0.f};

    f16x8 cur = sBs[lane];
    f32x4 dp[4];
    #pragma unroll
    for (int q = 0; q < 4; ++q)
        dp[q] = __builtin_amdgcn_mfma_f32_16x16x32_f16(afr[q], cur, zero, 0, 0, 0);

    #pragma unroll
    for (int jj = 1; jj < NT; ++jj) {
        cur = sBs[jj * 64 + lane];
        f32x4 dn[4];
        #pragma unroll
        for (int q = 0; q < 4; ++q)
            dn[q] = __builtin_amdgcn_mfma_f32_16x16x32_f16(afr[q], cur, zero, 0, 0, 0);
        // pack/min jj-1's results while jj's MFMAs are in flight
        #pragma unroll
        for (int q = 0; q < 4; ++q) {
            #pragma unroll
            for (int r = 0; r < 4; ++r) {
                unsigned pk = (__float_as_uint(dp[q][r]) & 0xFFFFFFE0u) | (unsigned)(jj - 1);
                bm[q * 4 + r] = fminf(bm[q * 4 + r], __uint_as_float(pk));
            }
        }
        #pragma unroll
        for (int q = 0; q < 4; ++q) dp[q] = dn[q];
    }
    #pragma unroll
    for (int q = 0; q < 4; ++q) {
        #pragma unroll
        for (int r = 0; r < 4; ++r) {
            unsigned pk = (__float_as_uint(dp[q][r]) & 0xFFFFFFE0u) | (unsigned)(NT - 1);
            bm[q * 4 + r] = fminf(bm[q * 4 + r], __uint_as_float(pk));
        }
    }

    const int g  = lane & 15;
    const int rb = (lane >> 4) << 2;
    #pragma unroll
    for (int q = 0; q < 4; ++q) {
        #pragma unroll
        for (int r = 0; r < 4; ++r) {
            const int row = (ti0 + q) * 16 + rb + r;
            part[row][g] = __float_as_uint(bm[q * 4 + r]);
        }
    }
}

// One block per batch, 1024 threads = 16 waves. Waves 0-7: pass 1 (input rows
// vs pred cols); waves 8-15: pass 2 operand-swapped. R18 structure (hist+KL
// before the scan) with ENCODE-ONCE staging: thread t owns one point
// (side = t>>9 wave-uniform, row = t&511), loads + encodes once, writes all
// four kg fragment slots. Same LDS bytes/layout as R13/R18.
__global__ __launch_bounds__(1024, 4)
void loss_kernel(const float* __restrict__ kine_input,
                 const float* __restrict__ class_input,
                 const float* __restrict__ kine_pred,
                 const float* __restrict__ class_pred,
                 const float* __restrict__ mu,
                 const float* __restrict__ log_var,
                 float* __restrict__ out)
{
    const int b    = (int)blockIdx.x;
    const int t    = (int)threadIdx.x;
    const int lane = t & 63;
    const int wave = t >> 6;

    __shared__ f16x8    sA[NT * 64];       // A' fragments (input side), 32 KB
    __shared__ f16x8    sB[NT * 64];       // B' fragments (pred side),  32 KB
    __shared__ unsigned part[2][NN][PG];   // packed per-(row, lane-group) minima, ~68 KB
    __shared__ float    red[16];
    __shared__ float    s_kl;
    __shared__ int      hist_in[DD], hist_pr[DD];

    if (t < DD) { hist_in[t] = 0; hist_pr[t] = 0; }

    // ---- hoisted epilogue operand: own class row (also feeds the histogram) ----
    const int ep_p  = t >> 9;
    const int ep_lr = t & (NN - 1);
    const float* own = (ep_p ? class_pred : class_input) + ((size_t)b * NN + ep_lr) * DD;
    float ownv[DD];
    #pragma unroll
    for (int d2 = 0; d2 < DD; ++d2) ownv[d2] = own[d2];

    // ---- encode-once staging: thread owns point (side, row); writes 4 kg slots ----
    // Layout (unchanged): slot = ti*64 + kg*16 + (row&15).
    // A: kg0 = [hi(-2x) x2], kg1 = [lo(-2x) x2], kg2 = [1,1,x2hi,x2lo, 0...].
    // B: kg0 = kg1 = [hi(y), lo(y)], kg2 = [y2hi,y2lo,1,1, 0...]. kg3 = zeros.
    {
        const int side = t >> 9;          // wave-uniform
        const int row  = t & (NN - 1);
        const int ti   = row >> 4;
        const int ri   = row & 15;
        const float* P = side ? kine_pred : kine_input;
        float4 pt = *reinterpret_cast<const float4*>(P + ((size_t)b * NN + row) * 4);
        const float n = pt.x*pt.x + pt.y*pt.y + pt.z*pt.z + pt.w*pt.w;
        float w[4];
        if (side == 0) { w[0] = -2.f*pt.x; w[1] = -2.f*pt.y; w[2] = -2.f*pt.z; w[3] = -2.f*pt.w; }
        else           { w[0] =      pt.x; w[1] =      pt.y; w[2] =      pt.z; w[3] =      pt.w; }
        _Float16 hi[4], lo[4];
        #pragma unroll
        for (int c = 0; c < 4; ++c) { hi[c] = (_Float16)w[c]; lo[c] = (_Float16)(w[c] - (float)hi[c]); }
        const _Float16 nhi = (_Float16)n;
        const _Float16 nlo = (_Float16)(n - (float)nhi);
        const _Float16 one = (_Float16)1.f;
        const _Float16 zz  = (_Float16)0.f;
        f16x8 hv0, hv1, hv2;
        const f16x8 hv3 = {zz, zz, zz, zz, zz, zz, zz, zz};
        if (side == 0) {
            hv0 = (f16x8){hi[0], hi[1], hi[2], hi[3], hi[0], hi[1], hi[2], hi[3]};
            hv1 = (f16x8){lo[0], lo[1], lo[2], lo[3], lo[0], lo[1], lo[2], lo[3]};
            hv2 = (f16x8){one,   one,   nhi,   nlo,   zz,    zz,    zz,    zz};
        } else {
            hv0 = (f16x8){hi[0], hi[1], hi[2], hi[3], lo[0], lo[1], lo[2], lo[3]};
            hv1 = hv0;
            hv2 = (f16x8){nhi,   nlo,   one,   one,   zz,    zz,    zz,    zz};
        }
        f16x8* dst = side ? sB : sA;
        dst[ti * 64 +      ri] = hv0;
        dst[ti * 64 + 16 + ri] = hv1;
        dst[ti * 64 + 32 + ri] = hv2;
        dst[ti * 64 + 48 + ri] = hv3;
    }
    __syncthreads();

    // ---- hist + KL BEFORE the scan (R18-proven overlap) ----
    {
        float mx = ownv[0]; int lab = 0;
        #pragma unroll
        for (int d2 = 1; d2 < DD; ++d2) { float v = ownv[d2]; if (v > mx) { mx = v; lab = d2; } }  // argmax(exp)==argmax
        atomicAdd(ep_p ? &hist_pr[lab] : &hist_in[lab], 1);
    }
    if (t < 64) {
        float v = 0.f;
        if (t < LL) {
            float m_ = mu[(size_t)b * LL + t];
            float lv = log_var[(size_t)b * LL + t];
            v = 1.f + lv - m_ * m_ - expf(lv);
        }
        #pragma unroll
        for (int off = 32; off > 0; off >>= 1) v += __shfl_down(v, off, 64);
        if (t == 0) s_kl = -0.5f * v;
    }

    // ---- concurrent transposed scans on wave halves ----
    if (wave < 8) min_scan4(sA, sB, part[0], wave,     lane);
    else          min_scan4(sB, sA, part[1], wave - 8, lane);
    __syncthreads();

    // ---- merge 16 groups + epilogue: thread t -> (pass ep_p, row ep_lr) ----
    // Ascending g with strict float <: (d_trunc, jj, g) lex == (d_trunc, col).
    float partsum;
    {
        const unsigned* pr = part[ep_p][ep_lr];
        unsigned e = pr[0]; int bg = 0;
        #pragma unroll
        for (int g = 1; g < 16; ++g) {
            unsigned v = pr[g];
            if (__uint_as_float(v) < __uint_as_float(e)) { e = v; bg = g; }
        }
        const int   idx  = bg + 16 * (int)(e & 31u);
        const float dmin = fmaxf(__uint_as_float(e & 0xFFFFFFE0u), 0.f);   // clamp commutes with min
        const float* oth = (ep_p ? class_input : class_pred) + ((size_t)b * NN + idx) * DD;
        float dot = 0.f;
        #pragma unroll
        for (int d2 = 0; d2 < DD; ++d2) dot += ownv[d2] * oth[d2];
        partsum = dmin - dot;   // chamfer + (-1)*class dot (W=1)
    }
    #pragma unroll
    for (int off = 32; off > 0; off >>= 1) partsum += __shfl_down(partsum, off, 64);
    if (lane == 0) red[wave] = partsum;
    __syncthreads();

    if (t == 0) {
        float sum = 0.f;
        #pragma unroll
        for (int w2 = 0; w2 < 16; ++w2) sum += red[w2];
        float cnum = 0.f;
        #pragma unroll
        for (int c = 0; c < DD; ++c) {
            float diff = fabsf((float)(hist_pr[c] - hist_in[c]));
            float wgt = (c == 0) ? 2.0f : ((c == DD - 1) ? 100.0f : 1.0f);
            cnum += wgt * diff;
        }
        out[b] = 0.99f * (sum + 0.001f * cnum) + 0.01f * s_kl;
    }
}

extern "C" void kernel_launch(void* const* d_in, const int* in_sizes, int n_in,
                              void* d_out, int out_size, void* d_ws, size_t ws_size,
                              hipStream_t stream) {
    const float* kine_input  = (const float*)d_in[0];
    const float* class_input = (const float*)d_in[1];
    const float* kine_pred   = (const float*)d_in[2];
    const float* class_pred  = (const float*)d_in[3];
    const float* mu          = (const float*)d_in[4];
    const float* log_var     = (const float*)d_in[5];
    float* out = (float*)d_out;

    loss_kernel<<<256, 1024, 0, stream>>>(kine_input, class_input, kine_pred,
                                          class_pred, mu, log_var, out);
}

// Round 21
// 17.137 us; speedup vs baseline: 1.0038x; 1.0038x over previous
//
#include <hip/hip_runtime.h>

#define NN 512
#define DD 9
#define LL 32
#define NT 32   // 16x16 tiles per dimension
#define PG 17   // part row stride (u32): odd -> conflict-free epilogue reads

typedef _Float16 f16x8 __attribute__((ext_vector_type(8)));
typedef float    f32x4 __attribute__((ext_vector_type(4)));

// Scan (R13-proven form: unconditional loads, dp/dn rotate pipeline, 60 VGPR,
// no spill — FROZEN). Wave wp owns 4 row-tiles {4wp..4wp+3} of the "a side",
// scans all 32 "b side" tiles. MFMA emits the complete distance (cross hi/lo
// split k0..15, norms k16..19). Tracking: pk = (dbits & ~31)|jj, fminf =
// 2 VALU/cell; per-lane (d_trunc, jj) min == first-index argmin over its col
// set col = (lane&15) + 16*jj (proven exact: R11/R13/R18 absmax 0.0).
__device__ __forceinline__ void min_scan4(const f16x8* __restrict__ sAs,
                                          const f16x8* __restrict__ sBs,
                                          unsigned (* __restrict__ part)[PG],
                                          int wp, int lane)
{
    const int ti0 = wp * 4;
    f16x8 afr[4];
    #pragma unroll
    for (int q = 0; q < 4; ++q) afr[q] = sAs[(ti0 + q) * 64 + lane];

    float bm[16];
    #pragma unroll
    for (int i = 0; i < 16; ++i) bm[i] = 1e30f;

    const f32x4 zero = {0.f, 0.f, 0.f, 0.f};

    f16x8 cur = sBs[lane];
    f32x4 dp[4];
    #pragma unroll
    for (int q = 0; q < 4; ++q)
        dp[q] = __builtin_amdgcn_mfma_f32_16x16x32_f16(afr[q], cur, zero, 0, 0, 0);

    #pragma unroll
    for (int jj = 1; jj < NT; ++jj) {
        cur = sBs[jj * 64 + lane];
        f32x4 dn[4];
        #pragma unroll
        for (int q = 0; q < 4; ++q)
            dn[q] = __builtin_amdgcn_mfma_f32_16x16x32_f16(afr[q], cur, zero, 0, 0, 0);
        // pack/min jj-1's results while jj's MFMAs are in flight
        #pragma unroll
        for (int q = 0; q < 4; ++q) {
            #pragma unroll
            for (int r = 0; r < 4; ++r) {
                unsigned pk = (__float_as_uint(dp[q][r]) & 0xFFFFFFE0u) | (unsigned)(jj - 1);
                bm[q * 4 + r] = fminf(bm[q * 4 + r], __uint_as_float(pk));
            }
        }
        #pragma unroll
        for (int q = 0; q < 4; ++q) dp[q] = dn[q];
    }
    #pragma unroll
    for (int q = 0; q < 4; ++q) {
        #pragma unroll
        for (int r = 0; r < 4; ++r) {
            unsigned pk = (__float_as_uint(dp[q][r]) & 0xFFFFFFE0u) | (unsigned)(NT - 1);
            bm[q * 4 + r] = fminf(bm[q * 4 + r], __uint_as_float(pk));
        }
    }

    const int g  = lane & 15;
    const int rb = (lane >> 4) << 2;
    #pragma unroll
    for (int q = 0; q < 4; ++q) {
        #pragma unroll
        for (int r = 0; r < 4; ++r) {
            const int row = (ti0 + q) * 16 + rb + r;
            part[row][g] = __float_as_uint(bm[q * 4 + r]);
        }
    }
}

// One block per batch, 1024 threads = 16 waves. Waves 0-7: pass 1 (input rows
// vs pred cols); waves 8-15: pass 2 operand-swapped. R18 structure (hist+KL
// before the scan) with ENCODE-ONCE staging: thread t owns one point
// (side = t>>9 wave-uniform, row = t&511), loads + encodes once, writes all
// four kg fragment slots. Same LDS bytes/layout as R13/R18.
__global__ __launch_bounds__(1024, 4)
void loss_kernel(const float* __restrict__ kine_input,
                 const float* __restrict__ class_input,
                 const float* __restrict__ kine_pred,
                 const float* __restrict__ class_pred,
                 const float* __restrict__ mu,
                 const float* __restrict__ log_var,
                 float* __restrict__ out)
{
    const int b    = (int)blockIdx.x;
    const int t    = (int)threadIdx.x;
    const int lane = t & 63;
    const int wave = t >> 6;

    __shared__ f16x8    sA[NT * 64];       // A' fragments (input side), 32 KB
    __shared__ f16x8    sB[NT * 64];       // B' fragments (pred side),  32 KB
    __shared__ unsigned part[2][NN][PG];   // packed per-(row, lane-group) minima, ~68 KB
    __shared__ float    red[16];
    __shared__ float    s_kl;
    __shared__ int      hist_in[DD], hist_pr[DD];

    if (t < DD) { hist_in[t] = 0; hist_pr[t] = 0; }

    // ---- hoisted epilogue operand: own class row (also feeds the histogram) ----
    const int ep_p  = t >> 9;
    const int ep_lr = t & (NN - 1);
    const float* own = (ep_p ? class_pred : class_input) + ((size_t)b * NN + ep_lr) * DD;
    float ownv[DD];
    #pragma unroll
    for (int d2 = 0; d2 < DD; ++d2) ownv[d2] = own[d2];

    // ---- encode-once staging: thread owns point (side, row); writes 4 kg slots ----
    // Layout (unchanged): slot = ti*64 + kg*16 + (row&15).
    // A: kg0 = [hi(-2x) x2], kg1 = [lo(-2x) x2], kg2 = [1,1,x2hi,x2lo, 0...].
    // B: kg0 = kg1 = [hi(y), lo(y)], kg2 = [y2hi,y2lo,1,1, 0...]. kg3 = zeros.
    {
        const int side = t >> 9;          // wave-uniform
        const int row  = t & (NN - 1);
        const int ti   = row >> 4;
        const int ri   = row & 15;
        const float* P = side ? kine_pred : kine_input;
        float4 pt = *reinterpret_cast<const float4*>(P + ((size_t)b * NN + row) * 4);
        const float n = pt.x*pt.x + pt.y*pt.y + pt.z*pt.z + pt.w*pt.w;
        float w[4];
        if (side == 0) { w[0] = -2.f*pt.x; w[1] = -2.f*pt.y; w[2] = -2.f*pt.z; w[3] = -2.f*pt.w; }
        else           { w[0] =      pt.x; w[1] =      pt.y; w[2] =      pt.z; w[3] =      pt.w; }
        _Float16 hi[4], lo[4];
        #pragma unroll
        for (int c = 0; c < 4; ++c) { hi[c] = (_Float16)w[c]; lo[c] = (_Float16)(w[c] - (float)hi[c]); }
        const _Float16 nhi = (_Float16)n;
        const _Float16 nlo = (_Float16)(n - (float)nhi);
        const _Float16 one = (_Float16)1.f;
        const _Float16 zz  = (_Float16)0.f;
        f16x8 hv0, hv1, hv2;
        const f16x8 hv3 = {zz, zz, zz, zz, zz, zz, zz, zz};
        if (side == 0) {
            hv0 = (f16x8){hi[0], hi[1], hi[2], hi[3], hi[0], hi[1], hi[2], hi[3]};
            hv1 = (f16x8){lo[0], lo[1], lo[2], lo[3], lo[0], lo[1], lo[2], lo[3]};
            hv2 = (f16x8){one,   one,   nhi,   nlo,   zz,    zz,    zz,    zz};
        } else {
            hv0 = (f16x8){hi[0], hi[1], hi[2], hi[3], lo[0], lo[1], lo[2], lo[3]};
            hv1 = hv0;
            hv2 = (f16x8){nhi,   nlo,   one,   one,   zz,    zz,    zz,    zz};
        }
        f16x8* dst = side ? sB : sA;
        dst[ti * 64 +      ri] = hv0;
        dst[ti * 64 + 16 + ri] = hv1;
        dst[ti * 64 + 32 + ri] = hv2;
        dst[ti * 64 + 48 + ri] = hv3;
    }
    __syncthreads();

    // ---- hist + KL BEFORE the scan (R18-proven overlap) ----
    {
        float mx = ownv[0]; int lab = 0;
        #pragma unroll
        for (int d2 = 1; d2 < DD; ++d2) { float v = ownv[d2]; if (v > mx) { mx = v; lab = d2; } }  // argmax(exp)==argmax
        atomicAdd(ep_p ? &hist_pr[lab] : &hist_in[lab], 1);
    }
    if (t < 64) {
        float v = 0.f;
        if (t < LL) {
            float m_ = mu[(size_t)b * LL + t];
            float lv = log_var[(size_t)b * LL + t];
            v = 1.f + lv - m_ * m_ - expf(lv);
        }
        #pragma unroll
        for (int off = 32; off > 0; off >>= 1) v += __shfl_down(v, off, 64);
        if (t == 0) s_kl = -0.5f * v;
    }

    // ---- concurrent transposed scans on wave halves ----
    if (wave < 8) min_scan4(sA, sB, part[0], wave,     lane);
    else          min_scan4(sB, sA, part[1], wave - 8, lane);
    __syncthreads();

    // ---- merge 16 groups + epilogue: thread t -> (pass ep_p, row ep_lr) ----
    // Ascending g with strict float <: (d_trunc, jj, g) lex == (d_trunc, col).
    float partsum;
    {
        const unsigned* pr = part[ep_p][ep_lr];
        unsigned e = pr[0]; int bg = 0;
        #pragma unroll
        for (int g = 1; g < 16; ++g) {
            unsigned v = pr[g];
            if (__uint_as_float(v) < __uint_as_float(e)) { e = v; bg = g; }
        }
        const int   idx  = bg + 16 * (int)(e & 31u);
        const float dmin = fmaxf(__uint_as_float(e & 0xFFFFFFE0u), 0.f);   // clamp commutes with min
        const float* oth = (ep_p ? class_input : class_pred) + ((size_t)b * NN + idx) * DD;
        float dot = 0.f;
        #pragma unroll
        for (int d2 = 0; d2 < DD; ++d2) dot += ownv[d2] * oth[d2];
        partsum = dmin - dot;   // chamfer + (-1)*class dot (W=1)
    }
    #pragma unroll
    for (int off = 32; off > 0; off >>= 1) partsum += __shfl_down(partsum, off, 64);
    if (lane == 0) red[wave] = partsum;
    __syncthreads();

    if (t == 0) {
        float sum = 0.f;
        #pragma unroll
        for (int w2 = 0; w2 < 16; ++w2) sum += red[w2];
        float cnum = 0.f;
        #pragma unroll
        for (int c = 0; c < DD; ++c) {
            float diff = fabsf((float)(hist_pr[c] - hist_in[c]));
            float wgt = (c == 0) ? 2.0f : ((c == DD - 1) ? 100.0f : 1.0f);
            cnum += wgt * diff;
        }
        out[b] = 0.99f * (sum + 0.001f * cnum) + 0.01f * s_kl;
    }
}

extern "C" void kernel_launch(void* const* d_in, const int* in_sizes, int n_in,
                              void* d_out, int out_size, void* d_ws, size_t ws_size,
                              hipStream_t stream) {
    const float* kine_input  = (const float*)d_in[0];
    const float* class_input = (const float*)d_in[1];
    const float* kine_pred   = (const float*)d_in[2];
    const float* class_pred  = (const float*)d_in[3];
    const float* mu          = (const float*)d_in[4];
    const float* log_var     = (const float*)d_in[5];
    float* out = (float*)d_out;

    loss_kernel<<<256, 1024, 0, stream>>>(kine_input, class_input, kine_pred,
                                          class_pred, mu, log_var, out);
}

// Round 22
// 16.743 us; speedup vs baseline: 1.0274x; 1.0235x over previous
//
#include <hip/hip_runtime.h>

#define NN 512
#define DD 9
#define LL 32
#define NT 32   // 16x16 tiles per dimension
#define PG 17   // part row stride (u32): odd -> conflict-free epilogue reads

typedef _Float16 f16x8 __attribute__((ext_vector_type(8)));
typedef float    f32x4 __attribute__((ext_vector_type(4)));

// Scan (R13-proven form: unconditional loads, dp/dn rotate pipeline, 60 VGPR,
// no spill — FROZEN). Wave wp owns 4 row-tiles {4wp..4wp+3} of the "a side",
// scans all 32 "b side" tiles. MFMA emits the complete distance (cross hi/lo
// split k0..15, norms k16..19). Tracking: pk = (dbits & ~31)|jj, fminf =
// 2 VALU/cell; per-lane (d_trunc, jj) min == first-index argmin over its col
// set col = (lane&15) + 16*jj (proven exact: R11/R13/R18/R21 absmax 0.0).
// KEY INVARIANT (enables barrier-free epilogue): wave wp writes ALL 16 g-slots
// of rows 64wp..64wp+63 itself — no other wave touches them.
__device__ __forceinline__ void min_scan4(const f16x8* __restrict__ sAs,
                                          const f16x8* __restrict__ sBs,
                                          unsigned (* __restrict__ part)[PG],
                                          int wp, int lane)
{
    const int ti0 = wp * 4;
    f16x8 afr[4];
    #pragma unroll
    for (int q = 0; q < 4; ++q) afr[q] = sAs[(ti0 + q) * 64 + lane];

    float bm[16];
    #pragma unroll
    for (int i = 0; i < 16; ++i) bm[i] = 1e30f;

    const f32x4 zero = {0.f, 0.f, 0.f, 0.f};

    f16x8 cur = sBs[lane];
    f32x4 dp[4];
    #pragma unroll
    for (int q = 0; q < 4; ++q)
        dp[q] = __builtin_amdgcn_mfma_f32_16x16x32_f16(afr[q], cur, zero, 0, 0, 0);

    #pragma unroll
    for (int jj = 1; jj < NT; ++jj) {
        cur = sBs[jj * 64 + lane];
        f32x4 dn[4];
        #pragma unroll
        for (int q = 0; q < 4; ++q)
            dn[q] = __builtin_amdgcn_mfma_f32_16x16x32_f16(afr[q], cur, zero, 0, 0, 0);
        // pack/min jj-1's results while jj's MFMAs are in flight
        #pragma unroll
        for (int q = 0; q < 4; ++q) {
            #pragma unroll
            for (int r = 0; r < 4; ++r) {
                unsigned pk = (__float_as_uint(dp[q][r]) & 0xFFFFFFE0u) | (unsigned)(jj - 1);
                bm[q * 4 + r] = fminf(bm[q * 4 + r], __uint_as_float(pk));
            }
        }
        #pragma unroll
        for (int q = 0; q < 4; ++q) dp[q] = dn[q];
    }
    #pragma unroll
    for (int q = 0; q < 4; ++q) {
        #pragma unroll
        for (int r = 0; r < 4; ++r) {
            unsigned pk = (__float_as_uint(dp[q][r]) & 0xFFFFFFE0u) | (unsigned)(NT - 1);
            bm[q * 4 + r] = fminf(bm[q * 4 + r], __uint_as_float(pk));
        }
    }

    const int g  = lane & 15;
    const int rb = (lane >> 4) << 2;
    #pragma unroll
    for (int q = 0; q < 4; ++q) {
        #pragma unroll
        for (int r = 0; r < 4; ++r) {
            const int row = (ti0 + q) * 16 + rb + r;
            part[row][g] = __float_as_uint(bm[q * 4 + r]);
        }
    }
}

// One block per batch, 1024 threads = 16 waves. Waves 0-7: pass 1 (input rows
// vs pred cols); waves 8-15: pass 2 operand-swapped. R21 structure (encode-
// once staging, hist+KL before the scan) with the POST-SCAN BARRIER REMOVED:
// each thread's merge reads only part entries written by its own wave (see
// invariant above), so scan -> merge -> gather flows without cross-wave sync;
// the single remaining barrier orders hist/s_kl/red for the t==0 finale.
__global__ __launch_bounds__(1024, 4)
void loss_kernel(const float* __restrict__ kine_input,
                 const float* __restrict__ class_input,
                 const float* __restrict__ kine_pred,
                 const float* __restrict__ class_pred,
                 const float* __restrict__ mu,
                 const float* __restrict__ log_var,
                 float* __restrict__ out)
{
    const int b    = (int)blockIdx.x;
    const int t    = (int)threadIdx.x;
    const int lane = t & 63;
    const int wave = t >> 6;

    __shared__ f16x8    sA[NT * 64];       // A' fragments (input side), 32 KB
    __shared__ f16x8    sB[NT * 64];       // B' fragments (pred side),  32 KB
    __shared__ unsigned part[2][NN][PG];   // packed per-(row, lane-group) minima, ~68 KB
    __shared__ float    red[16];
    __shared__ float    s_kl;
    __shared__ int      hist_in[DD], hist_pr[DD];

    if (t < DD) { hist_in[t] = 0; hist_pr[t] = 0; }

    // ---- hoisted epilogue operand: own class row (also feeds the histogram) ----
    const int ep_p  = t >> 9;
    const int ep_lr = t & (NN - 1);
    const float* own = (ep_p ? class_pred : class_input) + ((size_t)b * NN + ep_lr) * DD;
    float ownv[DD];
    #pragma unroll
    for (int d2 = 0; d2 < DD; ++d2) ownv[d2] = own[d2];

    // ---- encode-once staging: thread owns point (side, row); writes 4 kg slots ----
    // Layout (unchanged): slot = ti*64 + kg*16 + (row&15).
    // A: kg0 = [hi(-2x) x2], kg1 = [lo(-2x) x2], kg2 = [1,1,x2hi,x2lo, 0...].
    // B: kg0 = kg1 = [hi(y), lo(y)], kg2 = [y2hi,y2lo,1,1, 0...]. kg3 = zeros.
    {
        const int side = t >> 9;          // wave-uniform
        const int row  = t & (NN - 1);
        const int ti   = row >> 4;
        const int ri   = row & 15;
        const float* P = side ? kine_pred : kine_input;
        float4 pt = *reinterpret_cast<const float4*>(P + ((size_t)b * NN + row) * 4);
        const float n = pt.x*pt.x + pt.y*pt.y + pt.z*pt.z + pt.w*pt.w;
        float w[4];
        if (side == 0) { w[0] = -2.f*pt.x; w[1] = -2.f*pt.y; w[2] = -2.f*pt.z; w[3] = -2.f*pt.w; }
        else           { w[0] =      pt.x; w[1] =      pt.y; w[2] =      pt.z; w[3] =      pt.w; }
        _Float16 hi[4], lo[4];
        #pragma unroll
        for (int c = 0; c < 4; ++c) { hi[c] = (_Float16)w[c]; lo[c] = (_Float16)(w[c] - (float)hi[c]); }
        const _Float16 nhi = (_Float16)n;
        const _Float16 nlo = (_Float16)(n - (float)nhi);
        const _Float16 one = (_Float16)1.f;
        const _Float16 zz  = (_Float16)0.f;
        f16x8 hv0, hv1, hv2;
        const f16x8 hv3 = {zz, zz, zz, zz, zz, zz, zz, zz};
        if (side == 0) {
            hv0 = (f16x8){hi[0], hi[1], hi[2], hi[3], hi[0], hi[1], hi[2], hi[3]};
            hv1 = (f16x8){lo[0], lo[1], lo[2], lo[3], lo[0], lo[1], lo[2], lo[3]};
            hv2 = (f16x8){one,   one,   nhi,   nlo,   zz,    zz,    zz,    zz};
        } else {
            hv0 = (f16x8){hi[0], hi[1], hi[2], hi[3], lo[0], lo[1], lo[2], lo[3]};
            hv1 = hv0;
            hv2 = (f16x8){nhi,   nlo,   one,   one,   zz,    zz,    zz,    zz};
        }
        f16x8* dst = side ? sB : sA;
        dst[ti * 64 +      ri] = hv0;
        dst[ti * 64 + 16 + ri] = hv1;
        dst[ti * 64 + 32 + ri] = hv2;
        dst[ti * 64 + 48 + ri] = hv3;
    }
    __syncthreads();

    // ---- hist + KL BEFORE the scan (R18-proven overlap) ----
    {
        float mx = ownv[0]; int lab = 0;
        #pragma unroll
        for (int d2 = 1; d2 < DD; ++d2) { float v = ownv[d2]; if (v > mx) { mx = v; lab = d2; } }  // argmax(exp)==argmax
        atomicAdd(ep_p ? &hist_pr[lab] : &hist_in[lab], 1);
    }
    if (t < 64) {
        float v = 0.f;
        if (t < LL) {
            float m_ = mu[(size_t)b * LL + t];
            float lv = log_var[(size_t)b * LL + t];
            v = 1.f + lv - m_ * m_ - expf(lv);
        }
        #pragma unroll
        for (int off = 32; off > 0; off >>= 1) v += __shfl_down(v, off, 64);
        if (t == 0) s_kl = -0.5f * v;
    }

    // ---- concurrent transposed scans on wave halves (no barrier after!) ----
    if (wave < 8) min_scan4(sA, sB, part[0], wave,     lane);
    else          min_scan4(sB, sA, part[1], wave - 8, lane);

    // ---- merge 16 groups + epilogue: same-wave data only, barrier-free ----
    // 4-level tree; strict < keeps the lower-g block on ties == ascending-g
    // first-index semantics (g ascends within each tree pair by construction).
    float partsum;
    {
        const unsigned* pr = part[ep_p][ep_lr];
        float    dv[16];
        unsigned gv[16];
        #pragma unroll
        for (int g = 0; g < 16; ++g) { dv[g] = __uint_as_float(pr[g]); gv[g] = (unsigned)g; }
        #pragma unroll
        for (int s2 = 1; s2 < 16; s2 <<= 1) {
            #pragma unroll
            for (int i = 0; i < 16; i += 2 * s2) {
                if (dv[i + s2] < dv[i]) { dv[i] = dv[i + s2]; gv[i] = gv[i + s2]; }
            }
        }
        const unsigned e = __float_as_uint(dv[0]);
        const int   idx  = (int)gv[0] + 16 * (int)(e & 31u);
        const float dmin = fmaxf(__uint_as_float(e & 0xFFFFFFE0u), 0.f);   // clamp commutes with min
        const float* oth = (ep_p ? class_input : class_pred) + ((size_t)b * NN + idx) * DD;
        float dot = 0.f;
        #pragma unroll
        for (int d2 = 0; d2 < DD; ++d2) dot += ownv[d2] * oth[d2];
        partsum = dmin - dot;   // chamfer + (-1)*class dot (W=1)
    }
    #pragma unroll
    for (int off = 32; off > 0; off >>= 1) partsum += __shfl_down(partsum, off, 64);
    if (lane == 0) red[wave] = partsum;
    __syncthreads();   // single remaining barrier: orders red/hist/s_kl for t==0

    if (t == 0) {
        float sum = 0.f;
        #pragma unroll
        for (int w2 = 0; w2 < 16; ++w2) sum += red[w2];
        float cnum = 0.f;
        #pragma unroll
        for (int c = 0; c < DD; ++c) {
            float diff = fabsf((float)(hist_pr[c] - hist_in[c]));
            float wgt = (c == 0) ? 2.0f : ((c == DD - 1) ? 100.0f : 1.0f);
            cnum += wgt * diff;
        }
        out[b] = 0.99f * (sum + 0.001f * cnum) + 0.01f * s_kl;
    }
}

extern "C" void kernel_launch(void* const* d_in, const int* in_sizes, int n_in,
                              void* d_out, int out_size, void* d_ws, size_t ws_size,
                              hipStream_t stream) {
    const float* kine_input  = (const float*)d_in[0];
    const float* class_input = (const float*)d_in[1];
    const float* kine_pred   = (const float*)d_in[2];
    const float* class_pred  = (const float*)d_in[3];
    const float* mu          = (const float*)d_in[4];
    const float* log_var     = (const float*)d_in[5];
    float* out = (float*)d_out;

    loss_kernel<<<256, 1024, 0, stream>>>(kine_input, class_input, kine_pred,
                                          class_pred, mu, log_var, out);
}